// Round 1
// baseline (126.661 us; speedup 1.0000x reference)
//
#include <hip/hip_runtime.h>
#include <math.h>

#ifndef M_PI
#define M_PI 3.14159265358979323846
#endif

#define BATCHES   256
#define S_LEN     131072
#define CPB       1024     // chunks per batch row == threads per block
#define CHUNK     128      // S_LEN / CPB
#define SEG       (CPB/64) // chunks per lane in the phase-2 scan = 16

__device__ __forceinline__ void compute_coeffs(float level_in, float b0[3], float na1[3], float na2[3]) {
    const float FD[3] = {270.0f, 800.0f, 2300.0f};
    const float FN[3] = {500.0f, 1500.0f, 2500.0f};
    const float FB[3] = {730.0f, 2100.0f, 3000.0f};
    float level = fminf(fmaxf(level_in, 0.0f), 1.0f);
    float t_low  = fminf(fmaxf(level * 2.0f, 0.0f), 1.0f);
    float t_high = fminf(fmaxf((level - 0.5f) * 2.0f, 0.0f), 1.0f);
    bool hi = (level >= 0.5f);   // wave-uniform per block (same batch)
    const float W0 = (float)(2.0 * M_PI / 16000.0);
    #pragma unroll
    for (int k = 0; k < 3; ++k) {
        float f, q;
        if (hi) { f = (1.0f - t_high) * FN[k] + t_high * FB[k];
                  q = (1.0f - t_high) * 8.0f  + t_high * 12.0f; }
        else    { f = (1.0f - t_low) * FD[k] + t_low * FN[k];
                  q = (1.0f - t_low) * 5.0f  + t_low * 8.0f; }
        float omega = W0 * f;
        float sn = sinf(omega), cs = cosf(omega);
        float alpha = sn / (2.0f * fmaxf(q, 0.5f));
        float a0 = 1.0f + alpha;
        b0[k]  = alpha / a0;            // b2 == -b0 exactly
        na1[k] = (2.0f * cs) / a0;      // -a1
        na2[k] = -((1.0f - alpha) / a0);// -a2
    }
}

// one biquad step for all 3 bands; d = x[t] - x[t-2]
#define STEP(XT, XTM2, SUMV)                                                     \
    {                                                                            \
        float d = (XT) - (XTM2);                                                 \
        float yy0 = fmaf(b0[0], d, fmaf(na1[0], y1[0], na2[0] * y2[0]));         \
        float yy1 = fmaf(b0[1], d, fmaf(na1[1], y1[1], na2[1] * y2[1]));         \
        float yy2 = fmaf(b0[2], d, fmaf(na1[2], y1[2], na2[2] * y2[2]));         \
        y2[0] = y1[0]; y1[0] = yy0;                                              \
        y2[1] = y1[1]; y1[1] = yy1;                                              \
        y2[2] = y1[2]; y1[2] = yy2;                                              \
        SUMV = (yy0 + yy1 + yy2);                                                \
    }

__global__ __launch_bounds__(CPB) void formant_kernel(
    const float* __restrict__ x, const float* __restrict__ level_arr,
    float* __restrict__ out)
{
    const int b   = blockIdx.x;
    const int tid = threadIdx.x;
    const int c   = tid;                 // this thread's chunk within the row

    // stride-7 pad: phase-2 reads (lane*16+j)*7 -> 2-way bank aliasing (free)
    __shared__ float st[CPB][7];

    float b0[3], na1[3], na2[3];
    compute_coeffs(level_arr[b], b0, na1, na2);

    const float* xrow = x + (size_t)b * S_LEN;
    const float* xc   = xrow + c * CHUNK;
    const float xm1_0 = (c > 0) ? xc[-1] : 0.0f;   // true x history (only y-state is unknown)
    const float xm2_0 = (c > 0) ? xc[-2] : 0.0f;

    // ---------------- phase 1: zero-state response of this chunk ----------------
    {
        float y1[3] = {0.f, 0.f, 0.f}, y2[3] = {0.f, 0.f, 0.f};
        float xm1 = xm1_0, xm2 = xm2_0;
        const float4* xv = (const float4*)xc;
        float dummy;
        #pragma unroll 8
        for (int i = 0; i < CHUNK / 4; ++i) {
            float4 q = xv[i];
            STEP(q.x, xm2, dummy)
            STEP(q.y, xm1, dummy)
            STEP(q.z, q.x, dummy)
            STEP(q.w, q.y, dummy)
            xm2 = q.z; xm1 = q.w;
        }
        (void)dummy;
        st[c][0] = y1[0]; st[c][1] = y2[0];
        st[c][2] = y1[1]; st[c][3] = y2[1];
        st[c][4] = y1[2]; st[c][5] = y2[2];
    }
    __syncthreads();

    // ---------------- phase 2: affine scan over chunk-boundary states ----------------
    // s_{c+1} = zs_end_c + H * s_c,  H = [[h1[L-1], -a2*h1[L-2]], [h1[L-2], -a2*h1[L-3]]]
    {
        const int wave = tid >> 6, lane = tid & 63;
        if (wave < 3) {
            const int k = wave;
            const float A1 = (k == 0) ? na1[0] : ((k == 1) ? na1[1] : na1[2]);
            const float A2 = (k == 0) ? na2[0] : ((k == 1) ? na2[1] : na2[2]);
            // homogeneous solution h1 over one chunk
            float hm1 = 1.0f, hm2 = 0.0f, hm3 = 0.0f;
            for (int i = 0; i < CHUNK; ++i) {
                float h = fmaf(A1, hm1, A2 * hm2);
                hm3 = hm2; hm2 = hm1; hm1 = h;
            }
            const float H00 = hm1,      H01 = A2 * hm2;
            const float H10 = hm2,      H11 = A2 * hm3;

            // fold this lane's 16 chunks: b_l = sum_j H^{15-j} zs_j
            float s1 = 0.0f, s2 = 0.0f;
            #pragma unroll
            for (int j = 0; j < SEG; ++j) {
                int cc = lane * SEG + j;
                float z1 = st[cc][2 * k], z2 = st[cc][2 * k + 1];
                float n1 = z1 + H00 * s1 + H01 * s2;
                float n2 = z2 + H10 * s1 + H11 * s2;
                s1 = n1; s2 = n2;
            }
            // A = H^16 via 4 squarings
            float P00 = H00, P01 = H01, P10 = H10, P11 = H11;
            #pragma unroll
            for (int t = 0; t < 4; ++t) {
                float Q00 = P00 * P00 + P01 * P10;
                float Q01 = P00 * P01 + P01 * P11;
                float Q10 = P10 * P00 + P11 * P10;
                float Q11 = P10 * P01 + P11 * P11;
                P00 = Q00; P01 = Q01; P10 = Q10; P11 = Q11;
            }
            // Kogge-Stone inclusive scan of affine maps (A, b); compose cur ∘ incoming
            float A00 = P00, A01 = P01, A10 = P10, A11 = P11, bb1 = s1, bb2 = s2;
            for (int d = 1; d < 64; d <<= 1) {
                float iA00 = __shfl_up(A00, d), iA01 = __shfl_up(A01, d);
                float iA10 = __shfl_up(A10, d), iA11 = __shfl_up(A11, d);
                float ib1  = __shfl_up(bb1, d), ib2  = __shfl_up(bb2, d);
                if (lane >= d) {
                    float nb1 = A00 * ib1 + A01 * ib2 + bb1;
                    float nb2 = A10 * ib1 + A11 * ib2 + bb2;
                    float n00 = A00 * iA00 + A01 * iA10;
                    float n01 = A00 * iA01 + A01 * iA11;
                    float n10 = A10 * iA00 + A11 * iA10;
                    float n11 = A10 * iA01 + A11 * iA11;
                    A00 = n00; A01 = n01; A10 = n10; A11 = n11;
                    bb1 = nb1; bb2 = nb2;
                }
            }
            // exclusive: state entering this lane's segment (s_0 = 0 so it's just b)
            float e1 = __shfl_up(bb1, 1), e2 = __shfl_up(bb2, 1);
            if (lane == 0) { e1 = 0.0f; e2 = 0.0f; }
            // replay segment, overwriting LDS with the corrected entry state per chunk
            s1 = e1; s2 = e2;
            #pragma unroll
            for (int j = 0; j < SEG; ++j) {
                int cc = lane * SEG + j;
                float z1 = st[cc][2 * k], z2 = st[cc][2 * k + 1];
                st[cc][2 * k]     = s1;
                st[cc][2 * k + 1] = s2;
                float n1 = z1 + H00 * s1 + H01 * s2;
                float n2 = z2 + H10 * s1 + H11 * s2;
                s1 = n1; s2 = n2;
            }
        }
    }
    __syncthreads();

    // ---------------- phase 3: exact recurrence with corrected initial state ----------------
    {
        float y1[3], y2[3];
        y1[0] = st[c][0]; y2[0] = st[c][1];
        y1[1] = st[c][2]; y2[1] = st[c][3];
        y1[2] = st[c][4]; y2[2] = st[c][5];
        float xm1 = xm1_0, xm2 = xm2_0;
        const float4* xv = (const float4*)xc;
        float4* ov = (float4*)(out + (size_t)b * S_LEN + c * CHUNK);
        const float inv_sqrt_nb = 0.57735026918962576f;  // 1/sqrt(3)
        #pragma unroll 8
        for (int i = 0; i < CHUNK / 4; ++i) {
            float4 q = xv[i];
            float4 o;
            STEP(q.x, xm2, o.x)
            STEP(q.y, xm1, o.y)
            STEP(q.z, q.x, o.z)
            STEP(q.w, q.y, o.w)
            xm2 = q.z; xm1 = q.w;
            o.x *= inv_sqrt_nb; o.y *= inv_sqrt_nb;
            o.z *= inv_sqrt_nb; o.w *= inv_sqrt_nb;
            ov[i] = o;
        }
    }
}

extern "C" void kernel_launch(void* const* d_in, const int* in_sizes, int n_in,
                              void* d_out, int out_size, void* d_ws, size_t ws_size,
                              hipStream_t stream) {
    const float* audio = (const float*)d_in[0];
    const float* level = (const float*)d_in[1];
    float* out = (float*)d_out;
    (void)in_sizes; (void)n_in; (void)d_ws; (void)ws_size; (void)out_size;
    formant_kernel<<<BATCHES, CPB, 0, stream>>>(audio, level, out);
}